// Round 5
// baseline (165.625 us; speedup 1.0000x reference)
//
#include <hip/hip_runtime.h>
#include <hip/hip_bf16.h>
#include <cmath>

#define NROWS 32768
#define DIN   1024
#define DOUT  1024
#define BM    64
#define BK    32
#define NKT   (DIN / BK)   // 32 K-steps
#define MAXNORM 0.996f     // (1 - 4e-3)/sqrt(c), c = 1
#define XPAD  40           // Xt row = 80 B -> 2-way banks (free)

typedef __attribute__((ext_vector_type(8))) __bf16 bf16x8;
typedef __attribute__((ext_vector_type(4))) float  f32x4;
typedef __attribute__((ext_vector_type(2))) float  f32x2;
typedef __attribute__((ext_vector_type(4))) unsigned u32x4;

__device__ __forceinline__ unsigned pack2bf(float a, float b) {
    union { unsigned u; __bf16 h[2]; } p;
    p.h[0] = (__bf16)a; p.h[1] = (__bf16)b;
    return p.u;
}

// Fragment-ordered bf16 W pack: 16B chunk c = [kt(5)][j(6)][lane(6)],
// content = W[n][k0..k0+8) with n = j*16 + (lane&15), k0 = kt*32 + (lane>>4)*8.
// Wf read is non-temporal (one-shot); Wb stays cacheable (the hot operand).
__global__ void conv_w_kernel(const float* __restrict__ Wf, __bf16* __restrict__ Wb) {
    int c  = blockIdx.x * blockDim.x + threadIdx.x;   // 131072 chunks
    int l  = c & 63;
    int j  = (c >> 6) & 63;
    int kt = c >> 12;
    int n  = j * 16 + (l & 15);
    int k0 = kt * 32 + (l >> 4) * 8;
    const float* src = Wf + (size_t)n * DIN + k0;
    f32x4 v0 = __builtin_nontemporal_load((const f32x4*)src);
    f32x4 v1 = __builtin_nontemporal_load((const f32x4*)(src + 4));
    u32x4 o;
    o.x = pack2bf(v0[0], v0[1]); o.y = pack2bf(v0[2], v0[3]);
    o.z = pack2bf(v1[0], v1[1]); o.w = pack2bf(v1[2], v1[3]);
    *(u32x4*)((char*)Wb + (size_t)c * 16) = o;
}

// Fused bf16 MFMA GEMM (x @ W^T) + hyperbolic epilogue.
// 16 waves of 64r x 64c; W straight global->VGPR (L2-resident, cacheable);
// X via 4-buf LDS ring with static indices; X loads + out stores non-temporal
// so the 260 MB of streaming traffic does not evict the 2 MB W from L2.
__global__ __launch_bounds__(1024) void hyp_kernel_reg(
    const float* __restrict__ X,
    const __bf16* __restrict__ Wb,
    const float* __restrict__ bias,
    float* __restrict__ out)
{
    __shared__ __align__(16) __bf16 Xt[4][BM * XPAD];   // 20480 B ring
    __shared__ float hbs[DOUT];
    __shared__ float xsqs[BM];
    __shared__ float fco[BM][2];
    __shared__ float bred[16];

    const int tid  = threadIdx.x;
    const int lane = tid & 63;
    const int wid  = tid >> 6;       // 0..15 = 64-col group
    const int l15  = lane & 15;
    const int l4   = lane >> 4;
    const int row0 = blockIdx.x * BM;

    // x staging: thread -> (row, k-pair)
    const int xr = tid >> 4;         // 0..63
    const int xk = (tid & 15) * 2;   // 0..30
    const float* xp = X + (size_t)(row0 + xr) * DIN + xk;
    float xsq = 0.f;

    // per-wave W fragment base (elements); frag i at +i*512, K-step at +32768
    const __bf16* wp = Wb + ((size_t)(wid * 4) * 64 + lane) * 8;

    f32x4 acc[4][4];
    #pragma unroll
    for (int m = 0; m < 4; m++)
        #pragma unroll
        for (int n = 0; n < 4; n++)
            acc[m][n] = (f32x4){0.f, 0.f, 0.f, 0.f};

    // ---- prologue: issue first loads, overlap with hyp-bias compute ----
    f32x2 x0 = __builtin_nontemporal_load((const f32x2*)xp);            // tile 0
    f32x2 x1 = __builtin_nontemporal_load((const f32x2*)(xp + BK));     // tile 1
    bf16x8 bfr[4];
    #pragma unroll
    for (int i = 0; i < 4; i++) bfr[i] = *(const bf16x8*)(wp + i * 512);  // W(0)

    float bv = bias[tid];
    float bs = bv * bv;
    #pragma unroll
    for (int m = 1; m < 64; m <<= 1) bs += __shfl_xor(bs, m);
    if (lane == 0) bred[wid] = bs;
    __syncthreads();
    float tot = 0.f;
    #pragma unroll
    for (int i = 0; i < 16; i++) tot += bred[i];
    const float bnorm = sqrtf(fmaxf(tot, 1e-15f));
    const float bth   = tanhf(bnorm);          // ||expmap0(bias)||
    float sc0 = bth / bnorm;
    float hn  = bth;
    if (hn > MAXNORM) { sc0 *= MAXNORM / hn; hn = MAXNORM; }
    hbs[tid] = sc0 * bv;
    const float y2c = hn * hn;                 // ||hyp_bias||^2

    // stage tile 0 (x0 landed: the __syncthreads above drained vmcnt)
    xsq += x0[0] * x0[0] + x0[1] * x0[1];
    *(unsigned*)((char*)(&Xt[0][0]) + xr * (XPAD * 2) + xk * 2) = pack2bf(x0[0], x0[1]);
    x0 = x1;
    x1 = __builtin_nontemporal_load((const f32x2*)(xp + 2 * BK));       // tile 2

    // ---- K loop: 1 raw barrier/step; vmcnt never force-drained; ring-4 static ----
    auto step = [&](int kt, int rb, int wb) {
        if (kt + 1 < NKT) {                    // stage tile kt+1 (skip only garbage tail)
            xsq += x0[0] * x0[0] + x0[1] * x0[1];
            *(unsigned*)((char*)(&Xt[wb][0]) + xr * (XPAD * 2) + xk * 2) = pack2bf(x0[0], x0[1]);
        }
        x0 = x1;
        int xt = kt + 3 < NKT ? kt + 3 : NKT - 1;
        x1 = __builtin_nontemporal_load((const f32x2*)(xp + (size_t)xt * BK));

        asm volatile("s_waitcnt lgkmcnt(0)" ::: "memory");  // ds_writes visible
        __builtin_amdgcn_s_barrier();
        __builtin_amdgcn_sched_barrier(0);

        const char* xb = (const char*)(&Xt[rb][0]);
        bf16x8 a[4];
        #pragma unroll
        for (int m = 0; m < 4; m++)
            a[m] = *(const bf16x8*)(xb + ((m << 4) + l15) * (XPAD * 2) + (l4 << 4));

        __builtin_amdgcn_s_setprio(1);
        #pragma unroll
        for (int n = 0; n < 4; n++)
            #pragma unroll
            for (int m = 0; m < 4; m++)
                acc[m][n] = __builtin_amdgcn_mfma_f32_16x16x32_bf16(a[m], bfr[n], acc[m][n], 0, 0, 0);
        __builtin_amdgcn_s_setprio(0);

        int ktb = kt + 1 < NKT ? kt + 1 : NKT - 1;          // W(kt+1), L2-resident
        const __bf16* wkp = wp + (size_t)ktb * 32768;
        #pragma unroll
        for (int i = 0; i < 4; i++) bfr[i] = *(const bf16x8*)(wkp + i * 512);
    };

    for (int kt = 0; kt < NKT; kt += 4) {
        step(kt + 0, 0, 1);
        step(kt + 1, 1, 2);
        step(kt + 2, 2, 3);
        step(kt + 3, 3, 0);
    }

    __syncthreads();                            // loop done; full drain OK now

    // ---- row reductions (redq/redd alias the dead Xt ring) ----
    float* redq = (float*)(&Xt[0][0]);          // [64][16]
    float* redd = redq + BM * 16;               // 8 KB total <= 20480

    float xs = xsq;                             // 16 threads per row
    #pragma unroll
    for (int m = 1; m < 16; m <<= 1) xs += __shfl_xor(xs, m);
    if (l15 == 0) xsqs[xr] = xs;

    float hv[4];
    #pragma unroll
    for (int n = 0; n < 4; n++) hv[n] = hbs[(wid << 6) + (n << 4) + l15];

    #pragma unroll
    for (int m = 0; m < 4; m++) {
        #pragma unroll
        for (int r = 0; r < 4; r++) {
            float s = 0.f, d = 0.f;
            #pragma unroll
            for (int n = 0; n < 4; n++) {
                float v = acc[m][n][r];
                s += v * v;
                d += v * hv[n];
            }
            #pragma unroll
            for (int mm = 1; mm < 16; mm <<= 1) {   // cols live in low 4 lane bits
                s += __shfl_xor(s, mm);
                d += __shfl_xor(d, mm);
            }
            if (l15 == 0) {
                int rl = (m << 4) + (l4 << 2) + r;
                redq[rl * 16 + wid] = s;
                redd[rl * 16 + wid] = d;
            }
        }
    }
    __syncthreads();

    // ---- per-row scalars (64 threads) ----
    if (tid < BM) {
        int r = tid;
        float sq = 0.f, dt = 0.f;
        #pragma unroll
        for (int w = 0; w < 16; w++) { sq += redq[r * 16 + w]; dt += redd[r * 16 + w]; }
        float sx     = xsqs[r];
        float xnorm  = sqrtf(fmaxf(sx, 1e-15f));
        float mxnorm = sqrtf(fmaxf(sq, 1e-15f));
        float u  = fminf(xnorm, 1.f - 1e-5f);   // artanh clip
        float tv = tanhf(mxnorm / xnorm * atanhf(u));
        float rn = fminf(tv, MAXNORM);          // project(res) norm
        float s  = rn / mxnorm;
        float xy = s * dt;
        float x2 = rn * rn;
        float Am = 1.f + 2.f * xy + y2c;
        float Bm = 1.f - x2;
        float Dm = fmaxf(1.f + 2.f * xy + x2 * y2c, 1e-15f);
        float g1 = Am * s / Dm;
        float g2 = Bm / Dm;
        float osq   = g1 * g1 * sq + 2.f * g1 * g2 * dt + g2 * g2 * y2c;
        float onorm = sqrtf(fmaxf(osq, 1e-15f));
        float psc   = onorm > MAXNORM ? MAXNORM / onorm : 1.f;
        fco[r][0] = g1 * psc;
        fco[r][1] = g2 * psc;
    }
    __syncthreads();

    // ---- epilogue write (non-temporal: don't evict W) ----
    #pragma unroll
    for (int m = 0; m < 4; m++) {
        #pragma unroll
        for (int r = 0; r < 4; r++) {
            int rl = (m << 4) + (l4 << 2) + r;
            float F1 = fco[rl][0], F2 = fco[rl][1];
            float* orow = out + (size_t)(row0 + rl) * DOUT + (wid << 6);
            #pragma unroll
            for (int n = 0; n < 4; n++) {
                float v = F1 * acc[m][n][r] + F2 * hv[n];
                __builtin_nontemporal_store(v, orow + (n << 4) + l15);
            }
        }
    }
}

// Fallback (ws too small): round-2 verified structure, manual W pack, __syncthreads.
__global__ __launch_bounds__(512, 2) void hyp_kernel_basic(
    const float* __restrict__ X,
    const float* __restrict__ Wf,
    const float* __restrict__ bias,
    float* __restrict__ out)
{
    __shared__ __align__(16) __bf16 Wt[2][DOUT * BK];
    __shared__ __align__(16) __bf16 Xt[2][BM * XPAD];
    __shared__ float hbs[DOUT];
    __shared__ float redq[BM][8];
    __shared__ float redd[BM][8];
    __shared__ float xsqs[BM];
    __shared__ float fco[BM][2];
    __shared__ float bred[8];

    const int tid  = threadIdx.x;
    const int lane = tid & 63;
    const int wid  = tid >> 6;
    const int l15  = lane & 15;
    const int l4   = lane >> 4;
    const int row0 = blockIdx.x * BM;
    const int xr = tid >> 3;
    const int xk = (tid & 7) * 4;
    const float* xp = X + (size_t)(row0 + xr) * DIN + xk;
    float xsq = 0.f;

    f32x4 acc[4][8];
    #pragma unroll
    for (int m = 0; m < 4; m++)
        #pragma unroll
        for (int nt = 0; nt < 8; nt++)
            acc[m][nt] = (f32x4){0.f, 0.f, 0.f, 0.f};

    auto STAGE = [&](int buf, int kt) {
        if (kt < NKT) {
            #pragma unroll
            for (int j = 0; j < 8; j++) {
                int c = (j << 9) + tid;
                int q = c & 3, n = c >> 2;
                int k0 = kt * BK + ((q ^ ((n >> 1) & 3)) << 3);
                const float* src = Wf + (size_t)n * DIN + k0;
                f32x4 v0 = *(const f32x4*)src;
                f32x4 v1 = *(const f32x4*)(src + 4);
                u32x4 o;
                o.x = pack2bf(v0[0], v0[1]); o.y = pack2bf(v0[2], v0[3]);
                o.z = pack2bf(v1[0], v1[1]); o.w = pack2bf(v1[2], v1[3]);
                *(u32x4*)((char*)(&Wt[buf][0]) + c * 16) = o;
            }
            f32x4 xv = *(const f32x4*)(xp + kt * BK);
            xsq += xv[0]*xv[0] + xv[1]*xv[1] + xv[2]*xv[2] + xv[3]*xv[3];
            uint2 pk;
            pk.x = pack2bf(xv[0], xv[1]);
            pk.y = pack2bf(xv[2], xv[3]);
            *(uint2*)((char*)(&Xt[buf][0]) + xr * (XPAD * 2) + xk * 2) = pk;
        }
    };

    STAGE(0, 0);

    float b0 = bias[tid], b1 = bias[tid + 512];
    float bs = b0 * b0 + b1 * b1;
    #pragma unroll
    for (int m = 1; m < 64; m <<= 1) bs += __shfl_xor(bs, m);
    if (lane == 0) bred[wid] = bs;
    __syncthreads();
    float tot = 0.f;
    #pragma unroll
    for (int i = 0; i < 8; i++) tot += bred[i];
    const float bnorm = sqrtf(fmaxf(tot, 1e-15f));
    const float bth   = tanhf(bnorm);
    float sc0 = bth / bnorm;
    float hn  = bth;
    if (hn > MAXNORM) { sc0 *= MAXNORM / hn; hn = MAXNORM; }
    hbs[tid]       = sc0 * b0;
    hbs[tid + 512] = sc0 * b1;
    const float y2c = hn * hn;
    __syncthreads();

    float hv[8];
    #pragma unroll
    for (int nt = 0; nt < 8; nt++) hv[nt] = hbs[(wid << 7) + (nt << 4) + l15];

    int cur = 0;
    for (int kt = 0; kt < NKT; kt++) {
        STAGE(cur ^ 1, kt + 1);
        const char* xb = (const char*)(&Xt[cur][0]);
        const char* wb = (const char*)(&Wt[cur][0]);
        bf16x8 a[4], b[8];
        #pragma unroll
        for (int m = 0; m < 4; m++)
            a[m] = *(const bf16x8*)(xb + ((m << 4) + l15) * (XPAD * 2) + (l4 << 4));
        #pragma unroll
        for (int nt = 0; nt < 8; nt++) {
            int n = (wid << 7) + (nt << 4) + l15;
            b[nt] = *(const bf16x8*)(wb + n * 64 + ((l4 ^ ((n >> 1) & 3)) << 4));
        }
        #pragma unroll
        for (int m = 0; m < 4; m++)
            #pragma unroll
            for (int nt = 0; nt < 8; nt++)
                acc[m][nt] = __builtin_amdgcn_mfma_f32_16x16x32_bf16(a[m], b[nt], acc[m][nt], 0, 0, 0);
        __syncthreads();
        cur ^= 1;
    }

    float xs = xsq;
    #pragma unroll
    for (int m = 1; m < 8; m <<= 1) xs += __shfl_xor(xs, m);
    if ((tid & 7) == 0) xsqs[xr] = xs;

    #pragma unroll
    for (int m = 0; m < 4; m++) {
        #pragma unroll
        for (int r = 0; r < 4; r++) {
            float s = 0.f, d = 0.f;
            #pragma unroll
            for (int nt = 0; nt < 8; nt++) {
                float v = acc[m][nt][r];
                s += v * v;
                d += v * hv[nt];
            }
            #pragma unroll
            for (int mm = 1; mm < 16; mm <<= 1) {
                s += __shfl_xor(s, mm);
                d += __shfl_xor(d, mm);
            }
            if (l15 == 0) {
                int rl = (m << 4) + (l4 << 2) + r;
                redq[rl][wid] = s;
                redd[rl][wid] = d;
            }
        }
    }
    __syncthreads();

    if (tid < BM) {
        int r = tid;
        float sq = 0.f, dt = 0.f;
        #pragma unroll
        for (int w = 0; w < 8; w++) { sq += redq[r][w]; dt += redd[r][w]; }
        float sx     = xsqs[r];
        float xnorm  = sqrtf(fmaxf(sx, 1e-15f));
        float mxnorm = sqrtf(fmaxf(sq, 1e-15f));
        float u  = fminf(xnorm, 1.f - 1e-5f);
        float tv = tanhf(mxnorm / xnorm * atanhf(u));
        float rn = fminf(tv, MAXNORM);
        float s  = rn / mxnorm;
        float xy = s * dt;
        float x2 = rn * rn;
        float Am = 1.f + 2.f * xy + y2c;
        float Bm = 1.f - x2;
        float Dm = fmaxf(1.f + 2.f * xy + x2 * y2c, 1e-15f);
        float g1 = Am * s / Dm;
        float g2 = Bm / Dm;
        float osq   = g1 * g1 * sq + 2.f * g1 * g2 * dt + g2 * g2 * y2c;
        float onorm = sqrtf(fmaxf(osq, 1e-15f));
        float psc   = onorm > MAXNORM ? MAXNORM / onorm : 1.f;
        fco[r][0] = g1 * psc;
        fco[r][1] = g2 * psc;
    }
    __syncthreads();

    #pragma unroll
    for (int m = 0; m < 4; m++) {
        #pragma unroll
        for (int r = 0; r < 4; r++) {
            int rl = (m << 4) + (l4 << 2) + r;
            float F1 = fco[rl][0], F2 = fco[rl][1];
            float* orow = out + (size_t)(row0 + rl) * DOUT + (wid << 7);
            #pragma unroll
            for (int nt = 0; nt < 8; nt++)
                orow[(nt << 4) + l15] = F1 * acc[m][nt][r] + F2 * hv[nt];
        }
    }
}

extern "C" void kernel_launch(void* const* d_in, const int* in_sizes, int n_in,
                              void* d_out, int out_size, void* d_ws, size_t ws_size,
                              hipStream_t stream) {
    const float* X    = (const float*)d_in[0];
    const float* W    = (const float*)d_in[1];
    const float* bias = (const float*)d_in[2];
    float* out = (float*)d_out;

    const size_t wb_bytes = (size_t)DOUT * DIN * 2;
    if (ws_size >= wb_bytes) {
        __bf16* Wb = (__bf16*)d_ws;
        conv_w_kernel<<<dim3(512), dim3(256), 0, stream>>>(W, Wb);
        hyp_kernel_reg<<<dim3(NROWS / BM), dim3(1024), 0, stream>>>(X, Wb, bias, out);
    } else {
        hyp_kernel_basic<<<dim3(NROWS / BM), dim3(512), 0, stream>>>(X, W, bias, out);
    }
}

// Round 6
// 120.989 us; speedup vs baseline: 1.3689x; 1.3689x over previous
//
#include <hip/hip_runtime.h>
#include <hip/hip_bf16.h>
#include <cmath>

#define NROWS 32768
#define DIN   1024
#define DOUT  1024
#define BM    64
#define BK    32
#define NKT   (DIN / BK)   // 32 K-steps
#define MAXNORM 0.996f     // (1 - 4e-3)/sqrt(c), c = 1
#define XPAD  40           // Xt row = 80 B -> 2-way banks (free)

typedef __attribute__((ext_vector_type(8))) __bf16 bf16x8;
typedef __attribute__((ext_vector_type(4))) float  f32x4;
typedef __attribute__((ext_vector_type(2))) float  f32x2;
typedef __attribute__((ext_vector_type(4))) unsigned u32x4;

__device__ __forceinline__ unsigned pack2bf(float a, float b) {
    union { unsigned u; __bf16 h[2]; } p;
    p.h[0] = (__bf16)a; p.h[1] = (__bf16)b;
    return p.u;
}

// Fragment-ordered bf16 W pack: 16B chunk c = [kt(5)][j(6)][lane(6)],
// content = W[n][k0..k0+8) with n = j*16 + (lane&15), k0 = kt*32 + (lane>>4)*8.
__global__ void conv_w_kernel(const float* __restrict__ Wf, __bf16* __restrict__ Wb) {
    int c  = blockIdx.x * blockDim.x + threadIdx.x;   // 131072 chunks
    int l  = c & 63;
    int j  = (c >> 6) & 63;
    int kt = c >> 12;
    int n  = j * 16 + (l & 15);
    int k0 = kt * 32 + (l >> 4) * 8;
    const float* src = Wf + (size_t)n * DIN + k0;
    f32x4 v0 = *(const f32x4*)src;
    f32x4 v1 = *(const f32x4*)(src + 4);
    u32x4 o;
    o.x = pack2bf(v0[0], v0[1]); o.y = pack2bf(v0[2], v0[3]);
    o.z = pack2bf(v1[0], v1[1]); o.w = pack2bf(v1[2], v1[3]);
    *(u32x4*)((char*)Wb + (size_t)c * 16) = o;
}

// Fused bf16 MFMA GEMM (x @ W^T) + hyperbolic epilogue.
// 16 waves of 64r x 64c; W straight global->VGPR; X via 4-buf LDS ring.
// K-order staggered per block (kt0 = (bid>>3)&31) so co-XCD CUs read
// DIFFERENT 64KB W-slices each step (kills L2 hot-line multicast contention).
__global__ __launch_bounds__(1024) void hyp_kernel_reg(
    const float* __restrict__ X,
    const __bf16* __restrict__ Wb,
    const float* __restrict__ bias,
    float* __restrict__ out)
{
    __shared__ __align__(16) __bf16 Xt[4][BM * XPAD];   // 20480 B ring
    __shared__ float hbs[DOUT];
    __shared__ float xsqs[BM];
    __shared__ float fco[BM][2];
    __shared__ float bred[16];

    const int tid  = threadIdx.x;
    const int lane = tid & 63;
    const int wid  = tid >> 6;       // 0..15 = 64-col group
    const int l15  = lane & 15;
    const int l4   = lane >> 4;
    const int row0 = blockIdx.x * BM;
    const int kt0  = (blockIdx.x >> 3) & 31;   // K-order stagger (XCD-aware)

    // x staging: thread -> (row, k-pair)
    const int xr = tid >> 4;         // 0..63
    const int xk = (tid & 15) * 2;   // 0..30
    const float* xp = X + (size_t)(row0 + xr) * DIN + xk;
    float xsq = 0.f;

    // per-wave W fragment base (elements); frag i at +i*512, K-step at +32768
    const __bf16* wp = Wb + ((size_t)(wid * 4) * 64 + lane) * 8;

    auto ktOf = [&](int s) { return (kt0 + s) & 31; };

    f32x4 acc[4][4];
    #pragma unroll
    for (int m = 0; m < 4; m++)
        #pragma unroll
        for (int n = 0; n < 4; n++)
            acc[m][n] = (f32x4){0.f, 0.f, 0.f, 0.f};

    // ---- prologue: issue first loads, overlap with hyp-bias compute ----
    f32x2 x0 = *(const f32x2*)(xp + (size_t)ktOf(0) * BK);   // step 0
    f32x2 x1 = *(const f32x2*)(xp + (size_t)ktOf(1) * BK);   // step 1
    bf16x8 bfr[4];
    {
        const __bf16* wkp = wp + (size_t)ktOf(0) * 32768;
        #pragma unroll
        for (int i = 0; i < 4; i++) bfr[i] = *(const bf16x8*)(wkp + i * 512);
    }

    float bv = bias[tid];
    float bs = bv * bv;
    #pragma unroll
    for (int m = 1; m < 64; m <<= 1) bs += __shfl_xor(bs, m);
    if (lane == 0) bred[wid] = bs;
    __syncthreads();
    float tot = 0.f;
    #pragma unroll
    for (int i = 0; i < 16; i++) tot += bred[i];
    const float bnorm = sqrtf(fmaxf(tot, 1e-15f));
    const float bth   = tanhf(bnorm);          // ||expmap0(bias)||
    float sc0 = bth / bnorm;
    float hn  = bth;
    if (hn > MAXNORM) { sc0 *= MAXNORM / hn; hn = MAXNORM; }
    hbs[tid] = sc0 * bv;
    const float y2c = hn * hn;                 // ||hyp_bias||^2

    // stage step-0 tile (x0 landed: the __syncthreads above drained vmcnt)
    xsq += x0[0] * x0[0] + x0[1] * x0[1];
    *(unsigned*)((char*)(&Xt[0][0]) + xr * (XPAD * 2) + xk * 2) = pack2bf(x0[0], x0[1]);
    x0 = x1;
    x1 = *(const f32x2*)(xp + (size_t)ktOf(2) * BK);         // step 2

    // ---- K loop: 1 raw barrier/step; vmcnt never force-drained; ring-4 static ----
    auto step = [&](int s, int rb, int wb) {
        if (s + 1 < NKT) {                     // stage tile for step s+1
            xsq += x0[0] * x0[0] + x0[1] * x0[1];
            *(unsigned*)((char*)(&Xt[wb][0]) + xr * (XPAD * 2) + xk * 2) = pack2bf(x0[0], x0[1]);
        }
        x0 = x1;
        int sf = s + 3 < NKT ? s + 3 : NKT - 1;
        x1 = *(const f32x2*)(xp + (size_t)ktOf(sf) * BK);    // HBM, ~2 steps of flight

        asm volatile("s_waitcnt lgkmcnt(0)" ::: "memory");   // ds_writes visible
        __builtin_amdgcn_s_barrier();
        __builtin_amdgcn_sched_barrier(0);

        const char* xb = (const char*)(&Xt[rb][0]);
        bf16x8 a[4];
        #pragma unroll
        for (int m = 0; m < 4; m++)
            a[m] = *(const bf16x8*)(xb + ((m << 4) + l15) * (XPAD * 2) + (l4 << 4));

        __builtin_amdgcn_s_setprio(1);
        #pragma unroll
        for (int n = 0; n < 4; n++)
            #pragma unroll
            for (int m = 0; m < 4; m++)
                acc[m][n] = __builtin_amdgcn_mfma_f32_16x16x32_bf16(a[m], bfr[n], acc[m][n], 0, 0, 0);
        __builtin_amdgcn_s_setprio(0);

        int sb = s + 1 < NKT ? s + 1 : NKT - 1;              // W for step s+1, L2-resident
        const __bf16* wkp = wp + (size_t)ktOf(sb) * 32768;
        #pragma unroll
        for (int i = 0; i < 4; i++) bfr[i] = *(const bf16x8*)(wkp + i * 512);
    };

    for (int s = 0; s < NKT; s += 4) {
        step(s + 0, 0, 1);
        step(s + 1, 1, 2);
        step(s + 2, 2, 3);
        step(s + 3, 3, 0);
    }

    __syncthreads();                            // loop done; full drain OK now

    // ---- row reductions (redq/redd alias the dead Xt ring) ----
    float* redq = (float*)(&Xt[0][0]);          // [64][16]
    float* redd = redq + BM * 16;               // 8 KB total <= 20480

    float xs = xsq;                             // 16 threads per row
    #pragma unroll
    for (int m = 1; m < 16; m <<= 1) xs += __shfl_xor(xs, m);
    if (l15 == 0) xsqs[xr] = xs;

    float hv[4];
    #pragma unroll
    for (int n = 0; n < 4; n++) hv[n] = hbs[(wid << 6) + (n << 4) + l15];

    #pragma unroll
    for (int m = 0; m < 4; m++) {
        #pragma unroll
        for (int r = 0; r < 4; r++) {
            float s = 0.f, d = 0.f;
            #pragma unroll
            for (int n = 0; n < 4; n++) {
                float v = acc[m][n][r];
                s += v * v;
                d += v * hv[n];
            }
            #pragma unroll
            for (int mm = 1; mm < 16; mm <<= 1) {   // cols live in low 4 lane bits
                s += __shfl_xor(s, mm);
                d += __shfl_xor(d, mm);
            }
            if (l15 == 0) {
                int rl = (m << 4) + (l4 << 2) + r;
                redq[rl * 16 + wid] = s;
                redd[rl * 16 + wid] = d;
            }
        }
    }
    __syncthreads();

    // ---- per-row scalars (64 threads) ----
    if (tid < BM) {
        int r = tid;
        float sq = 0.f, dt = 0.f;
        #pragma unroll
        for (int w = 0; w < 16; w++) { sq += redq[r * 16 + w]; dt += redd[r * 16 + w]; }
        float sx     = xsqs[r];
        float xnorm  = sqrtf(fmaxf(sx, 1e-15f));
        float mxnorm = sqrtf(fmaxf(sq, 1e-15f));
        float u  = fminf(xnorm, 1.f - 1e-5f);   // artanh clip
        float tv = tanhf(mxnorm / xnorm * atanhf(u));
        float rn = fminf(tv, MAXNORM);          // project(res) norm
        float s  = rn / mxnorm;
        float xy = s * dt;
        float x2 = rn * rn;
        float Am = 1.f + 2.f * xy + y2c;
        float Bm = 1.f - x2;
        float Dm = fmaxf(1.f + 2.f * xy + x2 * y2c, 1e-15f);
        float g1 = Am * s / Dm;
        float g2 = Bm / Dm;
        float osq   = g1 * g1 * sq + 2.f * g1 * g2 * dt + g2 * g2 * y2c;
        float onorm = sqrtf(fmaxf(osq, 1e-15f));
        float psc   = onorm > MAXNORM ? MAXNORM / onorm : 1.f;
        fco[r][0] = g1 * psc;
        fco[r][1] = g2 * psc;
    }
    __syncthreads();

    // ---- epilogue write ----
    #pragma unroll
    for (int m = 0; m < 4; m++) {
        #pragma unroll
        for (int r = 0; r < 4; r++) {
            int rl = (m << 4) + (l4 << 2) + r;
            float F1 = fco[rl][0], F2 = fco[rl][1];
            float* orow = out + (size_t)(row0 + rl) * DOUT + (wid << 6);
            #pragma unroll
            for (int n = 0; n < 4; n++)
                orow[(n << 4) + l15] = F1 * acc[m][n][r] + F2 * hv[n];
        }
    }
}

// Fallback (ws too small): round-2 verified structure, manual W pack, __syncthreads.
__global__ __launch_bounds__(512, 2) void hyp_kernel_basic(
    const float* __restrict__ X,
    const float* __restrict__ Wf,
    const float* __restrict__ bias,
    float* __restrict__ out)
{
    __shared__ __align__(16) __bf16 Wt[2][DOUT * BK];
    __shared__ __align__(16) __bf16 Xt[2][BM * XPAD];
    __shared__ float hbs[DOUT];
    __shared__ float redq[BM][8];
    __shared__ float redd[BM][8];
    __shared__ float xsqs[BM];
    __shared__ float fco[BM][2];
    __shared__ float bred[8];

    const int tid  = threadIdx.x;
    const int lane = tid & 63;
    const int wid  = tid >> 6;
    const int l15  = lane & 15;
    const int l4   = lane >> 4;
    const int row0 = blockIdx.x * BM;
    const int xr = tid >> 3;
    const int xk = (tid & 7) * 4;
    const float* xp = X + (size_t)(row0 + xr) * DIN + xk;
    float xsq = 0.f;

    f32x4 acc[4][8];
    #pragma unroll
    for (int m = 0; m < 4; m++)
        #pragma unroll
        for (int nt = 0; nt < 8; nt++)
            acc[m][nt] = (f32x4){0.f, 0.f, 0.f, 0.f};

    auto STAGE = [&](int buf, int kt) {
        if (kt < NKT) {
            #pragma unroll
            for (int j = 0; j < 8; j++) {
                int c = (j << 9) + tid;
                int q = c & 3, n = c >> 2;
                int k0 = kt * BK + ((q ^ ((n >> 1) & 3)) << 3);
                const float* src = Wf + (size_t)n * DIN + k0;
                f32x4 v0 = *(const f32x4*)src;
                f32x4 v1 = *(const f32x4*)(src + 4);
                u32x4 o;
                o.x = pack2bf(v0[0], v0[1]); o.y = pack2bf(v0[2], v0[3]);
                o.z = pack2bf(v1[0], v1[1]); o.w = pack2bf(v1[2], v1[3]);
                *(u32x4*)((char*)(&Wt[buf][0]) + c * 16) = o;
            }
            f32x4 xv = *(const f32x4*)(xp + kt * BK);
            xsq += xv[0]*xv[0] + xv[1]*xv[1] + xv[2]*xv[2] + xv[3]*xv[3];
            uint2 pk;
            pk.x = pack2bf(xv[0], xv[1]);
            pk.y = pack2bf(xv[2], xv[3]);
            *(uint2*)((char*)(&Xt[buf][0]) + xr * (XPAD * 2) + xk * 2) = pk;
        }
    };

    STAGE(0, 0);

    float b0 = bias[tid], b1 = bias[tid + 512];
    float bs = b0 * b0 + b1 * b1;
    #pragma unroll
    for (int m = 1; m < 64; m <<= 1) bs += __shfl_xor(bs, m);
    if (lane == 0) bred[wid] = bs;
    __syncthreads();
    float tot = 0.f;
    #pragma unroll
    for (int i = 0; i < 8; i++) tot += bred[i];
    const float bnorm = sqrtf(fmaxf(tot, 1e-15f));
    const float bth   = tanhf(bnorm);
    float sc0 = bth / bnorm;
    float hn  = bth;
    if (hn > MAXNORM) { sc0 *= MAXNORM / hn; hn = MAXNORM; }
    hbs[tid]       = sc0 * b0;
    hbs[tid + 512] = sc0 * b1;
    const float y2c = hn * hn;
    __syncthreads();

    float hv[8];
    #pragma unroll
    for (int nt = 0; nt < 8; nt++) hv[nt] = hbs[(wid << 7) + (nt << 4) + l15];

    int cur = 0;
    for (int kt = 0; kt < NKT; kt++) {
        STAGE(cur ^ 1, kt + 1);
        const char* xb = (const char*)(&Xt[cur][0]);
        const char* wb = (const char*)(&Wt[cur][0]);
        bf16x8 a[4], b[8];
        #pragma unroll
        for (int m = 0; m < 4; m++)
            a[m] = *(const bf16x8*)(xb + ((m << 4) + l15) * (XPAD * 2) + (l4 << 4));
        #pragma unroll
        for (int nt = 0; nt < 8; nt++) {
            int n = (wid << 7) + (nt << 4) + l15;
            b[nt] = *(const bf16x8*)(wb + n * 64 + ((l4 ^ ((n >> 1) & 3)) << 4));
        }
        #pragma unroll
        for (int m = 0; m < 4; m++)
            #pragma unroll
            for (int nt = 0; nt < 8; nt++)
                acc[m][nt] = __builtin_amdgcn_mfma_f32_16x16x32_bf16(a[m], b[nt], acc[m][nt], 0, 0, 0);
        __syncthreads();
        cur ^= 1;
    }

    float xs = xsq;
    #pragma unroll
    for (int m = 1; m < 8; m <<= 1) xs += __shfl_xor(xs, m);
    if ((tid & 7) == 0) xsqs[xr] = xs;

    #pragma unroll
    for (int m = 0; m < 4; m++) {
        #pragma unroll
        for (int r = 0; r < 4; r++) {
            float s = 0.f, d = 0.f;
            #pragma unroll
            for (int nt = 0; nt < 8; nt++) {
                float v = acc[m][nt][r];
                s += v * v;
                d += v * hv[nt];
            }
            #pragma unroll
            for (int mm = 1; mm < 16; mm <<= 1) {
                s += __shfl_xor(s, mm);
                d += __shfl_xor(d, mm);
            }
            if (l15 == 0) {
                int rl = (m << 4) + (l4 << 2) + r;
                redq[rl][wid] = s;
                redd[rl][wid] = d;
            }
        }
    }
    __syncthreads();

    if (tid < BM) {
        int r = tid;
        float sq = 0.f, dt = 0.f;
        #pragma unroll
        for (int w = 0; w < 8; w++) { sq += redq[r][w]; dt += redd[r][w]; }
        float sx     = xsqs[r];
        float xnorm  = sqrtf(fmaxf(sx, 1e-15f));
        float mxnorm = sqrtf(fmaxf(sq, 1e-15f));
        float u  = fminf(xnorm, 1.f - 1e-5f);
        float tv = tanhf(mxnorm / xnorm * atanhf(u));
        float rn = fminf(tv, MAXNORM);
        float s  = rn / mxnorm;
        float xy = s * dt;
        float x2 = rn * rn;
        float Am = 1.f + 2.f * xy + y2c;
        float Bm = 1.f - x2;
        float Dm = fmaxf(1.f + 2.f * xy + x2 * y2c, 1e-15f);
        float g1 = Am * s / Dm;
        float g2 = Bm / Dm;
        float osq   = g1 * g1 * sq + 2.f * g1 * g2 * dt + g2 * g2 * y2c;
        float onorm = sqrtf(fmaxf(osq, 1e-15f));
        float psc   = onorm > MAXNORM ? MAXNORM / onorm : 1.f;
        fco[r][0] = g1 * psc;
        fco[r][1] = g2 * psc;
    }
    __syncthreads();

    #pragma unroll
    for (int m = 0; m < 4; m++) {
        #pragma unroll
        for (int r = 0; r < 4; r++) {
            int rl = (m << 4) + (l4 << 2) + r;
            float F1 = fco[rl][0], F2 = fco[rl][1];
            float* orow = out + (size_t)(row0 + rl) * DOUT + (wid << 7);
            #pragma unroll
            for (int nt = 0; nt < 8; nt++)
                orow[(nt << 4) + l15] = F1 * acc[m][nt][r] + F2 * hv[nt];
        }
    }
}

extern "C" void kernel_launch(void* const* d_in, const int* in_sizes, int n_in,
                              void* d_out, int out_size, void* d_ws, size_t ws_size,
                              hipStream_t stream) {
    const float* X    = (const float*)d_in[0];
    const float* W    = (const float*)d_in[1];
    const float* bias = (const float*)d_in[2];
    float* out = (float*)d_out;

    const size_t wb_bytes = (size_t)DOUT * DIN * 2;
    if (ws_size >= wb_bytes) {
        __bf16* Wb = (__bf16*)d_ws;
        conv_w_kernel<<<dim3(512), dim3(256), 0, stream>>>(W, Wb);
        hyp_kernel_reg<<<dim3(NROWS / BM), dim3(1024), 0, stream>>>(X, Wb, bias, out);
    } else {
        hyp_kernel_basic<<<dim3(NROWS / BM), dim3(512), 0, stream>>>(X, W, bias, out);
    }
}